// Round 1
// baseline (377.828 us; speedup 1.0000x reference)
//
#include <hip/hip_runtime.h>
#include <math.h>

#define BB 4
#define NN 4096
#define DD 128
#define HH 8
#define DHH 16
#define MM (BB*NN)   // 16384

// ---------------------------------------------------------------- layernorm
__global__ __launch_bounds__(128) void ln_kernel(const float* __restrict__ x,
                                                 const float* __restrict__ g,
                                                 const float* __restrict__ b,
                                                 float* __restrict__ out) {
    int row = blockIdx.x;
    int t = threadIdx.x;
    float v = x[(size_t)row * DD + t];
    float s = v, ss = v * v;
    #pragma unroll
    for (int o = 32; o > 0; o >>= 1) {
        s  += __shfl_xor(s, o);
        ss += __shfl_xor(ss, o);
    }
    __shared__ float red[4];
    int wid = t >> 6;
    if ((t & 63) == 0) { red[wid * 2] = s; red[wid * 2 + 1] = ss; }
    __syncthreads();
    s  = red[0] + red[2];
    ss = red[1] + red[3];
    float mu  = s * (1.0f / DD);
    float var = ss * (1.0f / DD) - mu * mu;
    float rs  = rsqrtf(var + 1e-6f);
    out[(size_t)row * DD + t] = (v - mu) * rs * g[t] + b[t];
}

// ---------------------------------------------------------------- generic GEMM
// C[m, col] = sum_d A[m,d] * W[col*128 + d]  (+bias, act, +resid)
// ACT: 0=none, 1=gelu(exact), 2=sigmoid
template <int ACT, bool HAS_BIAS, bool HAS_RES, bool PER_BATCH_W>
__global__ __launch_bounds__(256) void gemm128(const float* __restrict__ A,
                                               const float* __restrict__ W,
                                               const float* __restrict__ bias,
                                               const float* __restrict__ resid,
                                               float* __restrict__ C) {
    __shared__ float as[64 * 128];   // 32 KB
    __shared__ float wl[128 * 128];  // 64 KB, xor-swizzled in float4 units
    int t = threadIdx.x;
    int block_row = blockIdx.x * 64;

    const float4* A4 = (const float4*)(A + (size_t)block_row * DD);
    float4* as4w = (float4*)as;
    #pragma unroll
    for (int i = 0; i < 8; i++) {
        int j = i * 256 + t;          // 2048 float4
        as4w[j] = A4[j];
    }
    const float4* W4 = (const float4*)W + (PER_BATCH_W ? (size_t)(block_row >> 12) * 4096 : 0);
    float4* wl4w = (float4*)wl;
    #pragma unroll
    for (int i = 0; i < 16; i++) {
        int j = i * 256 + t;          // 4096 float4
        int r = j >> 5, c4 = j & 31;
        wl4w[r * 32 + (c4 ^ (r & 7))] = W4[j];
    }
    __syncthreads();

    const float4* as4 = (const float4*)as;
    const float4* wl4 = (const float4*)wl;
    int col = t & 127, rh = t >> 7;

    for (int rr = 0; rr < 32; rr += 2) {
        int ra = rh * 32 + rr;
        float s0 = 0.f, s1 = 0.f;
        #pragma unroll
        for (int d4 = 0; d4 < 32; d4++) {
            float4 w  = wl4[col * 32 + (d4 ^ (col & 7))];
            float4 a0 = as4[ra * 32 + d4];
            float4 a1 = as4[(ra + 1) * 32 + d4];
            s0 = fmaf(a0.x, w.x, s0); s0 = fmaf(a0.y, w.y, s0);
            s0 = fmaf(a0.z, w.z, s0); s0 = fmaf(a0.w, w.w, s0);
            s1 = fmaf(a1.x, w.x, s1); s1 = fmaf(a1.y, w.y, s1);
            s1 = fmaf(a1.z, w.z, s1); s1 = fmaf(a1.w, w.w, s1);
        }
        #pragma unroll
        for (int k = 0; k < 2; k++) {
            float s = (k == 0) ? s0 : s1;
            int row = block_row + ra + k;
            if (HAS_BIAS) s += bias[col];
            if (ACT == 1) s = 0.5f * s * (1.0f + erff(s * 0.70710678118654752f));
            if (ACT == 2) s = 1.0f / (1.0f + __expf(-s));
            if (HAS_RES)  s += resid[(size_t)row * DD + col];
            C[(size_t)row * DD + col] = s;
        }
    }
}

// ---------------------------------------------------------------- q softmax (groups of 16)
__global__ __launch_bounds__(256) void qsoftmax(float* __restrict__ q) {
    size_t idx = (size_t)blockIdx.x * 256 + threadIdx.x;
    float v = q[idx];
    float m = v;
    #pragma unroll
    for (int o = 8; o >= 1; o >>= 1) m = fmaxf(m, __shfl_xor(m, o));
    float e = __expf(v - m);
    float s = e;
    #pragma unroll
    for (int o = 8; o >= 1; o >>= 1) s += __shfl_xor(s, o);
    q[idx] = e / s;
}

// ---------------------------------------------------------------- k column stats (max, sum over n)
__global__ __launch_bounds__(256) void kstats(const float* __restrict__ k,
                                              float* __restrict__ cmax,
                                              float* __restrict__ csum) {
    int b = blockIdx.x >> 7, c = blockIdx.x & 127;
    int t = threadIdx.x;
    const float* base = k + (size_t)b * NN * DD + c;
    float m = -1e30f;
    for (int n = t; n < NN; n += 256) m = fmaxf(m, base[(size_t)n * DD]);
    #pragma unroll
    for (int o = 32; o > 0; o >>= 1) m = fmaxf(m, __shfl_xor(m, o));
    __shared__ float redm[4], reds[4];
    if ((t & 63) == 0) redm[t >> 6] = m;
    __syncthreads();
    m = fmaxf(fmaxf(redm[0], redm[1]), fmaxf(redm[2], redm[3]));
    float s = 0.f;
    for (int n = t; n < NN; n += 256) s += __expf(base[(size_t)n * DD] - m);
    #pragma unroll
    for (int o = 32; o > 0; o >>= 1) s += __shfl_xor(s, o);
    if ((t & 63) == 0) reds[t >> 6] = s;
    __syncthreads();
    if (t == 0) {
        cmax[blockIdx.x] = m;
        csum[blockIdx.x] = reds[0] + reds[1] + reds[2] + reds[3];
    }
}

// ---------------------------------------------------------------- ctx partials
// part[((b*8+h)*256 + d*16+e)*8 + chunk] = sum_{n in chunk} exp(k[n,hd]-max) * v[n,he]
__global__ __launch_bounds__(256) void ctx_partial(const float* __restrict__ klin,
                                                   const float* __restrict__ v,
                                                   const float* __restrict__ cmax,
                                                   float* __restrict__ part) {
    int b = blockIdx.x >> 6;
    int rem = blockIdx.x & 63;
    int h = rem >> 3, chunk = rem & 7;
    int t = threadIdx.x;
    int d = t >> 4, e = t & 15;

    __shared__ float ks_t[16 * 132];
    __shared__ float vs_t[16 * 132];
    const float* kb = klin + (size_t)b * NN * DD + h * DHH;
    const float* vb = v    + (size_t)b * NN * DD + h * DHH;
    const float* cm = cmax + b * DD + h * DHH;

    float acc = 0.f;
    for (int sc = 0; sc < 4; sc++) {
        int nb = chunk * 512 + sc * 128;
        __syncthreads();
        #pragma unroll
        for (int i = 0; i < 8; i++) {
            int idx = i * 256 + t;
            int r = idx >> 4, c = idx & 15;
            float kv = kb[(size_t)(nb + r) * DD + c];
            ks_t[c * 132 + r] = __expf(kv - cm[c]);
            vs_t[c * 132 + r] = vb[(size_t)(nb + r) * DD + c];
        }
        __syncthreads();
        const float4* ks4 = (const float4*)ks_t;
        const float4* vs4 = (const float4*)vs_t;
        #pragma unroll
        for (int i4 = 0; i4 < 32; i4++) {
            float4 kv = ks4[d * 33 + i4];
            float4 vv = vs4[e * 33 + i4];
            acc += kv.x * vv.x + kv.y * vv.y + kv.z * vv.z + kv.w * vv.w;
        }
    }
    part[(size_t)(((b * 8 + h) * 256 + d * 16 + e)) * 8 + chunk] = acc;
}

// ---------------------------------------------------------------- build Mt (folded ctx @ wo, transposed)
// Mt[b][ep*128 + c] = sum_e ctx[b, c/16, c%16, e] * wo[ep*128 + (c/16)*16 + e]
__global__ __launch_bounds__(256) void build_mt(const float* __restrict__ part,
                                                const float* __restrict__ csum,
                                                const float* __restrict__ wo,
                                                float* __restrict__ mt) {
    int b = blockIdx.x;
    int t = threadIdx.x;
    __shared__ float ctxL[2048];
    #pragma unroll
    for (int i = 0; i < 8; i++) {
        int idx = i * 256 + t;          // (h*16+d)*16 + e
        int e = idx & 15, hd = idx >> 4;
        int h = hd >> 4, d = hd & 15;
        const float* pp = part + (size_t)(((b * 8 + h) * 256 + d * 16 + e)) * 8;
        float s = 0.f;
        #pragma unroll
        for (int c = 0; c < 8; c++) s += pp[c];
        ctxL[idx] = s / csum[b * DD + h * DHH + d];
    }
    __syncthreads();
    for (int i = 0; i < 64; i++) {
        int j = i * 256 + t;
        int ep = j >> 7, c = j & 127;
        int h = c >> 4;
        float s = 0.f;
        #pragma unroll
        for (int e = 0; e < 16; e++)
            s += ctxL[c * 16 + e] * wo[ep * DD + h * DHH + e];
        mt[(size_t)b * 16384 + j] = s;
    }
}

// ---------------------------------------------------------------- S = x^T fx (per batch), stored transposed
// st[b][e*128 + d] = sum_n xf[b,n,d] * fx[b,n,e]
__global__ __launch_bounds__(256) void sbuild(const float* __restrict__ xf,
                                              const float* __restrict__ fx,
                                              float* __restrict__ st) {
    int b = blockIdx.x >> 6;
    int tile = blockIdx.x & 63;
    int d0 = (tile & 7) * 16, e0 = (tile >> 3) * 16;
    int t = threadIdx.x;
    int d = t >> 4, e = t & 15;

    __shared__ float xs_t[16 * 132];
    __shared__ float fs_t[16 * 132];
    const float* xb = xf + (size_t)b * NN * DD;
    const float* fb = fx + (size_t)b * NN * DD;

    float acc = 0.f;
    for (int n0 = 0; n0 < NN; n0 += 128) {
        __syncthreads();
        #pragma unroll
        for (int i = 0; i < 8; i++) {
            int idx = i * 256 + t;
            int r = idx >> 4, c = idx & 15;
            xs_t[c * 132 + r] = xb[(size_t)(n0 + r) * DD + d0 + c];
            fs_t[c * 132 + r] = fb[(size_t)(n0 + r) * DD + e0 + c];
        }
        __syncthreads();
        const float4* xs4 = (const float4*)xs_t;
        const float4* fs4 = (const float4*)fs_t;
        #pragma unroll
        for (int i4 = 0; i4 < 32; i4++) {
            float4 xv = xs4[d * 33 + i4];
            float4 fv = fs4[e * 33 + i4];
            acc += xv.x * fv.x + xv.y * fv.y + xv.z * fv.z + xv.w * fv.w;
        }
    }
    st[(size_t)b * 16384 + (e0 + e) * DD + (d0 + d)] = acc;
}

// ---------------------------------------------------------------- launch
extern "C" void kernel_launch(void* const* d_in, const int* in_sizes, int n_in,
                              void* d_out, int out_size, void* d_ws, size_t ws_size,
                              hipStream_t stream) {
    const float* x    = (const float*)d_in[0];
    const float* fx   = (const float*)d_in[1];
    const float* ln1g = (const float*)d_in[2];
    const float* ln1b = (const float*)d_in[3];
    const float* wq   = (const float*)d_in[4];
    const float* wk   = (const float*)d_in[5];
    const float* wv   = (const float*)d_in[6];
    const float* wo   = (const float*)d_in[7];
    const float* bo   = (const float*)d_in[8];
    const float* ln2g = (const float*)d_in[9];
    const float* ln2b = (const float*)d_in[10];
    const float* w1   = (const float*)d_in[11];
    const float* b1   = (const float*)d_in[12];
    const float* w2   = (const float*)d_in[13];
    const float* b2   = (const float*)d_in[14];

    float* out = (float*)d_out;
    float* xfinal = out;                       // output 0: x
    float* fxout  = out + (size_t)MM * DD;     // output 1: fx

    float* ws = (float*)d_ws;
    const size_t BUF = (size_t)MM * DD;        // 2,097,152 floats
    float* bufA = ws;
    float* bufB = ws + BUF;
    float* bufC = ws + 2 * BUF;
    float* bufD = ws + 3 * BUF;
    float* cmax = ws + 4 * BUF;                // 512
    float* csum = cmax + 512;                  // 512
    float* part = csum + 512;                  // 65536
    float* mt   = part + 65536;                // 65536
    float* st   = mt + 65536;                  // 65536

    // 1. ln1: x -> bufA (xn)
    ln_kernel<<<MM, 128, 0, stream>>>(x, ln1g, ln1b, bufA);
    // 2-4. q/k/v projections
    gemm128<0, false, false, false><<<MM / 64, 256, 0, stream>>>(bufA, wq, nullptr, nullptr, bufB);
    gemm128<0, false, false, false><<<MM / 64, 256, 0, stream>>>(bufA, wk, nullptr, nullptr, bufC);
    gemm128<0, false, false, false><<<MM / 64, 256, 0, stream>>>(bufA, wv, nullptr, nullptr, bufD);
    // 5. q softmax over dh (in place)
    qsoftmax<<<(MM * DD) / 256, 256, 0, stream>>>(bufB);
    // 6. k column stats
    kstats<<<BB * DD, 256, 0, stream>>>(bufC, cmax, csum);
    // 7. ctx partials
    ctx_partial<<<BB * HH * 8, 256, 0, stream>>>(bufC, bufD, cmax, part);
    // 8. fold ctx into wo -> per-batch Mt
    build_mt<<<BB, 256, 0, stream>>>(part, csum, wo, mt);
    // 9. x_mid = q @ Mt + bo + x -> bufA
    gemm128<0, true, true, true><<<MM / 64, 256, 0, stream>>>(bufB, mt, bo, x, bufA);
    // 10. ln2: bufA -> bufB
    ln_kernel<<<MM, 128, 0, stream>>>(bufA, ln2g, ln2b, bufB);
    // 11. h1 = gelu(bufB @ w1^T + b1) -> bufC
    gemm128<1, true, false, false><<<MM / 64, 256, 0, stream>>>(bufB, w1, b1, nullptr, bufC);
    // 12. x_final = bufC @ w2^T + b2 + bufA -> d_out (output 0)
    gemm128<0, true, true, false><<<MM / 64, 256, 0, stream>>>(bufC, w2, b2, bufA, xfinal);
    // 13. S = x_final^T fx per batch (transposed store)
    sbuild<<<BB * 64, 256, 0, stream>>>(xfinal, fx, st);
    // 14. fx_out = sigmoid(x_final @ S) -> d_out (output 1)
    gemm128<2, false, false, true><<<MM / 64, 256, 0, stream>>>(xfinal, st, nullptr, nullptr, fxout);
}

// Round 2
// 117.723 us; speedup vs baseline: 3.2095x; 3.2095x over previous
//
#include <hip/hip_runtime.h>
#include <math.h>

#define BB 4
#define NN 4096
#define DD 128
#define MM (BB*NN)   // 16384

typedef __attribute__((ext_vector_type(8))) short short8;
typedef __attribute__((ext_vector_type(4))) float f32x4;

__device__ inline short f2bf(float f) {
    unsigned u = __float_as_uint(f);
    u = (u + 0x7FFFu + ((u >> 16) & 1u)) >> 16;
    return (short)u;
}

__device__ inline short8 pack_bf8(float4 a, float4 b) {
    short8 o;
    o[0] = f2bf(a.x); o[1] = f2bf(a.y); o[2] = f2bf(a.z); o[3] = f2bf(a.w);
    o[4] = f2bf(b.x); o[5] = f2bf(b.y); o[6] = f2bf(b.z); o[7] = f2bf(b.w);
    return o;
}

// ---------------------------------------------------------------- layernorm (unchanged, correct)
__global__ __launch_bounds__(128) void ln_kernel(const float* __restrict__ x,
                                                 const float* __restrict__ g,
                                                 const float* __restrict__ b,
                                                 float* __restrict__ out) {
    int row = blockIdx.x;
    int t = threadIdx.x;
    float v = x[(size_t)row * DD + t];
    float s = v, ss = v * v;
    #pragma unroll
    for (int o = 32; o > 0; o >>= 1) {
        s  += __shfl_xor(s, o);
        ss += __shfl_xor(ss, o);
    }
    __shared__ float red[4];
    int wid = t >> 6;
    if ((t & 63) == 0) { red[wid * 2] = s; red[wid * 2 + 1] = ss; }
    __syncthreads();
    s  = red[0] + red[2];
    ss = red[1] + red[3];
    float mu  = s * (1.0f / DD);
    float var = ss * (1.0f / DD) - mu * mu;
    float rs  = rsqrtf(var + 1e-6f);
    out[(size_t)row * DD + t] = (v - mu) * rs * g[t] + b[t];
}

// ---------------------------------------------------------------- weight preconvert to bf16 frag layout
// frag slot j = nt*256 + ks*64 + l ; elem i (0..7) = W[nt*16 + (l&15)][32*ks + 8*(l>>4) + i]
__global__ __launch_bounds__(256) void wprep(const float* __restrict__ w0, const float* __restrict__ w1,
                                             const float* __restrict__ w2, const float* __restrict__ w3,
                                             const float* __restrict__ w4, short* __restrict__ wf) {
    int m = blockIdx.x >> 3;
    int j = (blockIdx.x & 7) * 256 + threadIdx.x;
    const float* W = (m == 0) ? w0 : (m == 1) ? w1 : (m == 2) ? w2 : (m == 3) ? w3 : w4;
    int nt = j >> 8, ks = (j >> 6) & 3, l = j & 63, r = l & 15, g = l >> 4;
    const float* src = W + (size_t)(nt * 16 + r) * DD + 32 * ks + 8 * g;
    float4 a = *(const float4*)src;
    float4 b = *(const float4*)(src + 4);
    ((short8*)(wf + (size_t)m * 16384))[j] = pack_bf8(a, b);
}

// ---------------------------------------------------------------- MFMA GEMM
// C[m,col] = sum_k A[m,k]*Wfrag(col,k)  (+bias, act, +resid)
// ACT: 0=none, 1=gelu(exact), 2=sigmoid, 3=softmax over 16-col head groups, 4=exp
template <int ACT, bool HAS_BIAS, bool HAS_RES, bool PBW>
__global__ __launch_bounds__(256) void gemm_mfma(const float* __restrict__ A,
                                                 const short* __restrict__ wfrag,
                                                 const float* __restrict__ bias,
                                                 const float* __restrict__ resid,
                                                 float* __restrict__ C) {
    __shared__ __align__(16) short wl[16384];   // 32 KB, frag-ordered bf16 W
    int t = threadIdx.x;
    int block_row = blockIdx.x * 32;
    const float4* ws4 = (const float4*)(wfrag + (PBW ? (size_t)(block_row >> 12) * 16384 : 0));
    float4* wl4 = (float4*)wl;
    #pragma unroll
    for (int i = 0; i < 8; i++) wl4[i * 256 + t] = ws4[i * 256 + t];

    int w = t >> 6, l = t & 63, r = l & 15, g = l >> 4;
    int row0 = block_row + ((w >> 1) << 4);     // wave's 16-row tile
    int nt0 = (w & 1) << 2;                     // wave's 4 col-tiles
    const float* ap = A + (size_t)(row0 + r) * DD + 8 * g;
    float4 av0[4], av1[4];
    #pragma unroll
    for (int ks = 0; ks < 4; ks++) {
        av0[ks] = *(const float4*)(ap + 32 * ks);
        av1[ks] = *(const float4*)(ap + 32 * ks + 4);
    }
    __syncthreads();

    f32x4 acc[4];
    #pragma unroll
    for (int n = 0; n < 4; n++) acc[n] = (f32x4){0.f, 0.f, 0.f, 0.f};
    const short8* wl8 = (const short8*)wl;
    #pragma unroll
    for (int ks = 0; ks < 4; ks++) {
        short8 af = pack_bf8(av0[ks], av1[ks]);
        #pragma unroll
        for (int n = 0; n < 4; n++)
            acc[n] = __builtin_amdgcn_mfma_f32_16x16x32_bf16(
                af, wl8[((nt0 + n) * 4 + ks) * 64 + l], acc[n], 0, 0, 0);
    }

    #pragma unroll
    for (int n = 0; n < 4; n++) {
        int col = (nt0 + n) * 16 + r;
        float bv = HAS_BIAS ? bias[col] : 0.0f;
        #pragma unroll
        for (int j = 0; j < 4; j++) {
            float v = acc[n][j] + bv;
            if (ACT == 1) v = 0.5f * v * (1.0f + erff(v * 0.70710678118654752f));
            else if (ACT == 2) v = 1.0f / (1.0f + __expf(-v));
            else if (ACT == 3) {
                float e = __expf(v);
                float s = e;
                s += __shfl_xor(s, 1); s += __shfl_xor(s, 2);
                s += __shfl_xor(s, 4); s += __shfl_xor(s, 8);
                v = e / s;
            }
            else if (ACT == 4) v = __expf(v);
            size_t row = (size_t)(row0 + 4 * g + j);
            if (HAS_RES) v += resid[row * DD + col];
            C[row * DD + col] = v;
        }
    }
}

// ---------------------------------------------------------------- ctx partials per (b,h,128-row chunk)
// part[bi*256 + d*16+e] = sum_r ek[r, h*16+d] * v[r, h*16+e] ; pcs[bi*16+d] = sum_r ek[r, h*16+d]
__global__ __launch_bounds__(256) void ctxp(const float* __restrict__ ek, const float* __restrict__ v,
                                            float* __restrict__ part, float* __restrict__ pcs) {
    int bi = blockIdx.x;                 // (b*8+h)*32 + chunk
    int chunk = bi & 31, bh = bi >> 5, h = bh & 7, b = bh >> 3;
    int t = threadIdx.x;
    __shared__ float eks[16 * 132], vs[16 * 132];   // transposed [c][row], padded
    const float* eb = ek + ((size_t)b * NN + chunk * 128) * DD + h * 16;
    const float* vb = v  + ((size_t)b * NN + chunk * 128) * DD + h * 16;
    #pragma unroll
    for (int i = 0; i < 2; i++) {
        int idx = i * 256 + t;           // 512 float4: row = idx>>2, c4 = idx&3
        int row = idx >> 2, c = (idx & 3) * 4;
        float4 ev = *(const float4*)(eb + (size_t)row * DD + c);
        float4 vv = *(const float4*)(vb + (size_t)row * DD + c);
        eks[(c+0)*132+row] = ev.x; eks[(c+1)*132+row] = ev.y; eks[(c+2)*132+row] = ev.z; eks[(c+3)*132+row] = ev.w;
        vs [(c+0)*132+row] = vv.x; vs [(c+1)*132+row] = vv.y; vs [(c+2)*132+row] = vv.z; vs [(c+3)*132+row] = vv.w;
    }
    __syncthreads();
    int d = t >> 4, e = t & 15;
    float acc = 0.f, cs = 0.f;
    #pragma unroll 8
    for (int r4 = 0; r4 < 128; r4 += 4) {
        float4 ev = *(const float4*)(eks + d * 132 + r4);
        float4 vv = *(const float4*)(vs  + e * 132 + r4);
        acc += ev.x * vv.x + ev.y * vv.y + ev.z * vv.z + ev.w * vv.w;
        cs  += ev.x + ev.y + ev.z + ev.w;
    }
    part[(size_t)bi * 256 + t] = acc;
    if (e == 0) pcs[(size_t)bi * 16 + d] = cs;
}

// ---------------------------------------------------------------- ctx reduce + fold wo -> mt frag (bf16)
// Mbig[k=h*16+d][ep] = sum_eo (ctx[h,d,eo]/csum[h,d]) * wo[ep*128 + h*16+eo]
// grid = b*8 + nt ; each block emits the 256 frag slots of its nt
__global__ __launch_bounds__(256) void build_mt_k(const float* __restrict__ part,
                                                  const float* __restrict__ pcs,
                                                  const float* __restrict__ wo,
                                                  short* __restrict__ mtfrag) {
    int b = blockIdx.x >> 3, nt = blockIdx.x & 7;
    int t = threadIdx.x;
    __shared__ float ctxL[2048];    // [k][eo] raw sums
    __shared__ float csL[128];
    __shared__ float woL[2048];     // rows ep = nt*16+rr, all 128 d
    #pragma unroll
    for (int i = 0; i < 8; i++) {
        int idx = i * 256 + t;
        int h = idx >> 8, rem = idx & 255;
        const float* pp = part + ((size_t)(b * 8 + h) * 32) * 256 + rem;
        float s = 0.f;
        #pragma unroll 8
        for (int c = 0; c < 32; c++) s += pp[(size_t)c * 256];
        ctxL[idx] = s;
    }
    if (t < 128) {
        int h = t >> 4, d = t & 15;
        const float* qq = pcs + ((size_t)(b * 8 + h) * 32) * 16 + d;
        float s = 0.f;
        #pragma unroll 8
        for (int c = 0; c < 32; c++) s += qq[(size_t)c * 16];
        csL[t] = s;
    }
    #pragma unroll
    for (int i = 0; i < 8; i++) {
        int idx = i * 256 + t;
        woL[idx] = wo[(size_t)(nt * 16) * DD + idx];
    }
    __syncthreads();
    int ks = (t >> 6) & 3, l = t & 63, r = l & 15, g = l >> 4;
    short8 o;
    #pragma unroll
    for (int i2 = 0; i2 < 8; i2++) {
        int k = 32 * ks + 8 * g + i2;
        float inv = 1.0f / csL[k];
        const float* wrow = woL + r * DD + (k >> 4) * 16;
        float s = 0.f;
        #pragma unroll
        for (int eo = 0; eo < 16; eo++) s += ctxL[k * 16 + eo] * wrow[eo];
        o[i2] = f2bf(s * inv);
    }
    ((short8*)(mtfrag + (size_t)b * 16384))[nt * 256 + t] = o;
}

// ---------------------------------------------------------------- S partials: S[d,e] = sum_n x[n,d] fx[n,e]
// grid = b*64 + chunk(64 rows) ; part stored as [bi][e*128 + d]
__global__ __launch_bounds__(256) void sbuild_p(const float* __restrict__ xf,
                                                const float* __restrict__ fx,
                                                float* __restrict__ part) {
    int b = blockIdx.x >> 6, chunk = blockIdx.x & 63;
    int t = threadIdx.x;
    __shared__ float xs[64 * 128], fs[64 * 128];
    const float* xb = xf + ((size_t)b * NN + chunk * 64) * DD;
    const float* fb = fx + ((size_t)b * NN + chunk * 64) * DD;
    float4* xs4 = (float4*)xs; float4* fs4 = (float4*)fs;
    const float4* xg = (const float4*)xb; const float4* fg = (const float4*)fb;
    #pragma unroll
    for (int i = 0; i < 8; i++) {
        int j = i * 256 + t;
        xs4[j] = xg[j]; fs4[j] = fg[j];
    }
    __syncthreads();
    int td = t >> 4, te = t & 15;
    float acc[8][8];
    #pragma unroll
    for (int a = 0; a < 8; a++)
        #pragma unroll
        for (int c = 0; c < 8; c++) acc[a][c] = 0.f;
    for (int r = 0; r < 64; r++) {
        float4 x0 = xs4[r * 32 + td * 2], x1 = xs4[r * 32 + td * 2 + 1];
        float4 f0 = fs4[r * 32 + te * 2], f1 = fs4[r * 32 + te * 2 + 1];
        float xv[8] = {x0.x, x0.y, x0.z, x0.w, x1.x, x1.y, x1.z, x1.w};
        float fv[8] = {f0.x, f0.y, f0.z, f0.w, f1.x, f1.y, f1.z, f1.w};
        #pragma unroll
        for (int a = 0; a < 8; a++)
            #pragma unroll
            for (int c = 0; c < 8; c++) acc[a][c] = fmaf(xv[a], fv[c], acc[a][c]);
    }
    float* pb = part + (size_t)blockIdx.x * 16384;
    int d0 = td * 8, e0 = te * 8;
    #pragma unroll
    for (int ei = 0; ei < 8; ei++) {
        float4 v0 = {acc[0][ei], acc[1][ei], acc[2][ei], acc[3][ei]};
        float4 v1 = {acc[4][ei], acc[5][ei], acc[6][ei], acc[7][ei]};
        float4* dst = (float4*)(pb + (size_t)(e0 + ei) * DD + d0);
        dst[0] = v0; dst[1] = v1;
    }
}

// ---------------------------------------------------------------- reduce S partials -> st frag (bf16)
// Wst(col=e, k=d) = S[d][e] ; frag elem i = S[32ks+8g+i][nt*16+r]
__global__ __launch_bounds__(256) void sreduce(const float* __restrict__ part,
                                               short* __restrict__ stfrag) {
    int b = blockIdx.x >> 3;
    int j = (blockIdx.x & 7) * 256 + threadIdx.x;
    int nt = j >> 8, ks = (j >> 6) & 3, l = j & 63, r = l & 15, g = l >> 4;
    int c = nt * 16 + r, k0 = 32 * ks + 8 * g;
    const float* pb = part + (size_t)b * 64 * 16384 + (size_t)c * DD + k0;
    float s[8] = {0.f, 0.f, 0.f, 0.f, 0.f, 0.f, 0.f, 0.f};
    for (int ch = 0; ch < 64; ch++) {
        const float4* p4 = (const float4*)(pb + (size_t)ch * 16384);
        float4 u0 = p4[0], u1 = p4[1];
        s[0] += u0.x; s[1] += u0.y; s[2] += u0.z; s[3] += u0.w;
        s[4] += u1.x; s[5] += u1.y; s[6] += u1.z; s[7] += u1.w;
    }
    short8 o;
    #pragma unroll
    for (int i = 0; i < 8; i++) o[i] = f2bf(s[i]);
    ((short8*)(stfrag + (size_t)b * 16384))[j] = o;
}

// ---------------------------------------------------------------- launch
extern "C" void kernel_launch(void* const* d_in, const int* in_sizes, int n_in,
                              void* d_out, int out_size, void* d_ws, size_t ws_size,
                              hipStream_t stream) {
    const float* x    = (const float*)d_in[0];
    const float* fx   = (const float*)d_in[1];
    const float* ln1g = (const float*)d_in[2];
    const float* ln1b = (const float*)d_in[3];
    const float* wq   = (const float*)d_in[4];
    const float* wk   = (const float*)d_in[5];
    const float* wv   = (const float*)d_in[6];
    const float* wo   = (const float*)d_in[7];
    const float* bo   = (const float*)d_in[8];
    const float* ln2g = (const float*)d_in[9];
    const float* ln2b = (const float*)d_in[10];
    const float* w1   = (const float*)d_in[11];
    const float* b1   = (const float*)d_in[12];
    const float* w2   = (const float*)d_in[13];
    const float* b2   = (const float*)d_in[14];

    float* out = (float*)d_out;
    float* xfinal = out;
    float* fxout  = out + (size_t)MM * DD;

    float* ws = (float*)d_ws;
    const size_t BUF = (size_t)MM * DD;       // 2,097,152 floats
    float* B0 = ws;
    float* B1 = ws + BUF;
    float* B2 = ws + 2 * BUF;
    float* B3 = ws + 3 * BUF;
    float* partC = ws + 4 * BUF;              // 262144 floats
    float* pcs   = partC + 262144;            // 16384
    short* wfW   = (short*)(pcs + 16384);     // 5*16384 shorts
    short* mtf   = wfW + 5 * 16384;           // 4*16384
    short* stf   = mtf + 4 * 16384;           // 4*16384
    float* partS = B1;                        // 4*64*16384 floats = spans B1..B2

    ln_kernel<<<MM, 128, 0, stream>>>(x, ln1g, ln1b, B0);
    wprep<<<40, 256, 0, stream>>>(wq, wk, wv, w1, w2, wfW);
    // q (fused feature-softmax), ek (fused exp), v
    gemm_mfma<3, false, false, false><<<512, 256, 0, stream>>>(B0, wfW,             nullptr, nullptr, B1);
    gemm_mfma<4, false, false, false><<<512, 256, 0, stream>>>(B0, wfW + 16384,     nullptr, nullptr, B2);
    gemm_mfma<0, false, false, false><<<512, 256, 0, stream>>>(B0, wfW + 2 * 16384, nullptr, nullptr, B3);
    ctxp<<<1024, 256, 0, stream>>>(B2, B3, partC, pcs);
    build_mt_k<<<32, 256, 0, stream>>>(partC, pcs, wo, mtf);
    // x_mid = q @ Mbig + bo + x
    gemm_mfma<0, true, true, true><<<512, 256, 0, stream>>>(B1, mtf, bo, x, B0);
    ln_kernel<<<MM, 128, 0, stream>>>(B0, ln2g, ln2b, B2);
    // h1 = gelu(y@w1 + b1)
    gemm_mfma<1, true, false, false><<<512, 256, 0, stream>>>(B2, wfW + 3 * 16384, b1, nullptr, B3);
    // x_final = h1@w2 + b2 + x_mid  -> output 0
    gemm_mfma<0, true, true, false><<<512, 256, 0, stream>>>(B3, wfW + 4 * 16384, b2, B0, xfinal);
    // quadratic update via S = x^T fx
    sbuild_p<<<256, 256, 0, stream>>>(xfinal, fx, partS);
    sreduce<<<32, 256, 0, stream>>>(partS, stf);
    gemm_mfma<2, false, false, true><<<512, 256, 0, stream>>>(xfinal, stf, nullptr, nullptr, fxout);
}

// Round 3
// 111.134 us; speedup vs baseline: 3.3997x; 1.0593x over previous
//
#include <hip/hip_runtime.h>
#include <math.h>

#define BB 4
#define NN 4096
#define DD 128
#define MM (BB*NN)   // 16384

typedef __attribute__((ext_vector_type(8))) short short8;
typedef __attribute__((ext_vector_type(4))) float f32x4;

__device__ inline short f2bf(float f) {
    unsigned u = __float_as_uint(f);
    u = (u + 0x7FFFu + ((u >> 16) & 1u)) >> 16;
    return (short)u;
}
__device__ inline float bf2f(short s) {
    return __uint_as_float(((unsigned)(unsigned short)s) << 16);
}
__device__ inline short8 pack_bf8(float4 a, float4 b) {
    short8 o;
    o[0] = f2bf(a.x); o[1] = f2bf(a.y); o[2] = f2bf(a.z); o[3] = f2bf(a.w);
    o[4] = f2bf(b.x); o[5] = f2bf(b.y); o[6] = f2bf(b.z); o[7] = f2bf(b.w);
    return o;
}

// ---------------------------------------------------------------- weight preconvert to bf16 frag layout
// frag slot j = nt*256 + ks*64 + l ; elem i (0..7) = W[nt*16 + (l&15)][32*ks + 8*(l>>4) + i]
__global__ __launch_bounds__(256) void wprep(const float* __restrict__ w0, const float* __restrict__ w1,
                                             const float* __restrict__ w2, const float* __restrict__ w3,
                                             const float* __restrict__ w4, short* __restrict__ wf) {
    int m = blockIdx.x >> 3;
    int j = (blockIdx.x & 7) * 256 + threadIdx.x;
    const float* W = (m == 0) ? w0 : (m == 1) ? w1 : (m == 2) ? w2 : (m == 3) ? w3 : w4;
    int nt = j >> 8, ks = (j >> 6) & 3, l = j & 63, r = l & 15, g = l >> 4;
    const float* src = W + (size_t)(nt * 16 + r) * DD + 32 * ks + 8 * g;
    float4 a = *(const float4*)src;
    float4 b = *(const float4*)(src + 4);
    ((short8*)(wf + (size_t)m * 16384))[j] = pack_bf8(a, b);
}

// ---------------------------------------------------------------- fused LN1 + QKV (+q softmax, +k exp)
__global__ __launch_bounds__(256) void lnqkv(const float* __restrict__ x,
                                             const float* __restrict__ lng,
                                             const float* __restrict__ lnb,
                                             const short* __restrict__ wf,
                                             short* __restrict__ qb,
                                             short* __restrict__ ekb,
                                             short* __restrict__ vb) {
    int t = threadIdx.x;
    int block_row = blockIdx.x * 32;
    int w = t >> 6, l = t & 63, r = l & 15, g = l >> 4;
    int row0 = block_row + ((w >> 1) << 4);
    int nt0 = (w & 1) << 2;

    const float* ap = x + (size_t)(row0 + r) * DD + 8 * g;
    float4 av0[4], av1[4];
    #pragma unroll
    for (int ks = 0; ks < 4; ks++) {
        av0[ks] = *(const float4*)(ap + 32 * ks);
        av1[ks] = *(const float4*)(ap + 32 * ks + 4);
    }
    float s = 0.f, ss = 0.f;
    #pragma unroll
    for (int ks = 0; ks < 4; ks++) {
        float4 a = av0[ks], b = av1[ks];
        s  += a.x + a.y + a.z + a.w + b.x + b.y + b.z + b.w;
        ss += a.x*a.x + a.y*a.y + a.z*a.z + a.w*a.w + b.x*b.x + b.y*b.y + b.z*b.z + b.w*b.w;
    }
    s  += __shfl_xor(s, 16);  s  += __shfl_xor(s, 32);
    ss += __shfl_xor(ss, 16); ss += __shfl_xor(ss, 32);
    float mu = s * (1.0f / DD);
    float var = ss * (1.0f / DD) - mu * mu;
    float rs = rsqrtf(var + 1e-6f);

    short8 af[4];
    #pragma unroll
    for (int ks = 0; ks < 4; ks++) {
        float4 g0 = *(const float4*)(lng + 32 * ks + 8 * g);
        float4 g1 = *(const float4*)(lng + 32 * ks + 8 * g + 4);
        float4 b0 = *(const float4*)(lnb + 32 * ks + 8 * g);
        float4 b1 = *(const float4*)(lnb + 32 * ks + 8 * g + 4);
        float4 n0, n1;
        n0.x = (av0[ks].x - mu) * rs * g0.x + b0.x;
        n0.y = (av0[ks].y - mu) * rs * g0.y + b0.y;
        n0.z = (av0[ks].z - mu) * rs * g0.z + b0.z;
        n0.w = (av0[ks].w - mu) * rs * g0.w + b0.w;
        n1.x = (av1[ks].x - mu) * rs * g1.x + b1.x;
        n1.y = (av1[ks].y - mu) * rs * g1.y + b1.y;
        n1.z = (av1[ks].z - mu) * rs * g1.z + b1.z;
        n1.w = (av1[ks].w - mu) * rs * g1.w + b1.w;
        af[ks] = pack_bf8(n0, n1);
    }

    f32x4 acc[3][4];
    #pragma unroll
    for (int m = 0; m < 3; m++)
        #pragma unroll
        for (int n = 0; n < 4; n++) acc[m][n] = (f32x4){0.f, 0.f, 0.f, 0.f};
    const short8* wp8 = (const short8*)wf;
    #pragma unroll
    for (int ks = 0; ks < 4; ks++)
        #pragma unroll
        for (int m = 0; m < 3; m++)
            #pragma unroll
            for (int n = 0; n < 4; n++)
                acc[m][n] = __builtin_amdgcn_mfma_f32_16x16x32_bf16(
                    af[ks], wp8[(size_t)m * 2048 + ((nt0 + n) * 4 + ks) * 64 + l], acc[m][n], 0, 0, 0);

    #pragma unroll
    for (int n = 0; n < 4; n++) {
        int col = (nt0 + n) * 16 + r;
        #pragma unroll
        for (int j = 0; j < 4; j++) {
            size_t row = (size_t)(row0 + 4 * g + j);
            // q: softmax over the 16 cols of this head (spread over r-lanes)
            float e = __expf(acc[0][n][j]);
            float sm = e;
            sm += __shfl_xor(sm, 1); sm += __shfl_xor(sm, 2);
            sm += __shfl_xor(sm, 4); sm += __shfl_xor(sm, 8);
            qb[row * DD + col]  = f2bf(e / sm);
            ekb[row * DD + col] = f2bf(__expf(acc[1][n][j]));
            vb[row * DD + col]  = f2bf(acc[2][n][j]);
        }
    }
}

// ---------------------------------------------------------------- generic bf16 MFMA GEMM with fused epilogues
// ACT: 0=none, 1=gelu(exact), 2=sigmoid ; LNF: layernorm epilogue (Cf=raw f32, Cb=normed bf16)
template <int ACT, bool BIASF, bool RESF, bool PBW, bool WF, bool WB, bool LNF>
__global__ __launch_bounds__(256) void gemm_b(const short* __restrict__ A,
                                              const short* __restrict__ wfrag,
                                              const float* __restrict__ bias,
                                              const float* __restrict__ resid,
                                              const float* __restrict__ lng,
                                              const float* __restrict__ lnb,
                                              float* __restrict__ Cf,
                                              short* __restrict__ Cb) {
    int t = threadIdx.x;
    int block_row = blockIdx.x * 32;
    int w = t >> 6, l = t & 63, r = l & 15, g = l >> 4;
    int row0 = block_row + ((w >> 1) << 4);
    int nt0 = (w & 1) << 2;

    const short8* ap = (const short8*)(A + (size_t)(row0 + r) * DD + 8 * g);
    short8 af[4];
    #pragma unroll
    for (int ks = 0; ks < 4; ks++) af[ks] = ap[ks * 4];

    const short8* wp8 = (const short8*)(wfrag + (PBW ? (size_t)(block_row >> 12) * 16384 : 0));
    f32x4 acc[4];
    #pragma unroll
    for (int n = 0; n < 4; n++) acc[n] = (f32x4){0.f, 0.f, 0.f, 0.f};
    #pragma unroll
    for (int ks = 0; ks < 4; ks++)
        #pragma unroll
        for (int n = 0; n < 4; n++)
            acc[n] = __builtin_amdgcn_mfma_f32_16x16x32_bf16(
                af[ks], wp8[((nt0 + n) * 4 + ks) * 64 + l], acc[n], 0, 0, 0);

    float vv[4][4];
    #pragma unroll
    for (int n = 0; n < 4; n++) {
        int col = (nt0 + n) * 16 + r;
        float bv = BIASF ? bias[col] : 0.0f;
        #pragma unroll
        for (int j = 0; j < 4; j++) {
            float v = acc[n][j] + bv;
            if (ACT == 1) v = 0.5f * v * (1.0f + erff(v * 0.70710678118654752f));
            else if (ACT == 2) v = 1.0f / (1.0f + __expf(-v));
            if (RESF) v += resid[(size_t)(row0 + 4 * g + j) * DD + col];
            vv[n][j] = v;
            if (WF) Cf[(size_t)(row0 + 4 * g + j) * DD + col] = v;
            if (WB && !LNF) Cb[(size_t)(row0 + 4 * g + j) * DD + col] = f2bf(v);
        }
    }

    if (LNF) {
        __shared__ float redS[4][16], redSS[4][16];
        #pragma unroll
        for (int j = 0; j < 4; j++) {
            float s  = vv[0][j] + vv[1][j] + vv[2][j] + vv[3][j];
            float s2 = vv[0][j]*vv[0][j] + vv[1][j]*vv[1][j] + vv[2][j]*vv[2][j] + vv[3][j]*vv[3][j];
            s  += __shfl_xor(s, 1);  s  += __shfl_xor(s, 2);  s  += __shfl_xor(s, 4);  s  += __shfl_xor(s, 8);
            s2 += __shfl_xor(s2, 1); s2 += __shfl_xor(s2, 2); s2 += __shfl_xor(s2, 4); s2 += __shfl_xor(s2, 8);
            if (r == 0) { redS[w][4 * g + j] = s; redSS[w][4 * g + j] = s2; }
        }
        __syncthreads();
        int base = w & 2;
        #pragma unroll
        for (int j = 0; j < 4; j++) {
            int rr = 4 * g + j;
            float S  = redS[base][rr]  + redS[base + 1][rr];
            float SS = redSS[base][rr] + redSS[base + 1][rr];
            float mu = S * (1.0f / DD);
            float var = SS * (1.0f / DD) - mu * mu;
            float rs = rsqrtf(var + 1e-6f);
            #pragma unroll
            for (int n = 0; n < 4; n++) {
                int col = (nt0 + n) * 16 + r;
                Cb[(size_t)(row0 + rr) * DD + col] = f2bf((vv[n][j] - mu) * rs * lng[col] + lnb[col]);
            }
        }
    }
}

// ---------------------------------------------------------------- ctx partials per (b,h,128-row chunk), bf16 in
__global__ __launch_bounds__(256) void ctxp(const short* __restrict__ ek, const short* __restrict__ v,
                                            float* __restrict__ part, float* __restrict__ pcs) {
    int bi = blockIdx.x;                 // (b*8+h)*32 + chunk
    int chunk = bi & 31, bh = bi >> 5, h = bh & 7, b = bh >> 3;
    int t = threadIdx.x;
    __shared__ float eks[16 * 132], vs[16 * 132];
    const short* eb = ek + ((size_t)b * NN + chunk * 128) * DD + h * 16;
    const short* vb = v  + ((size_t)b * NN + chunk * 128) * DD + h * 16;
    {
        int row = t >> 1, half = t & 1;
        short8 es = *(const short8*)(eb + (size_t)row * DD + half * 8);
        short8 vsv = *(const short8*)(vb + (size_t)row * DD + half * 8);
        #pragma unroll
        for (int i = 0; i < 8; i++) {
            int c = half * 8 + i;
            eks[c * 132 + row] = bf2f(es[i]);
            vs [c * 132 + row] = bf2f(vsv[i]);
        }
    }
    __syncthreads();
    int d = t >> 4, e = t & 15;
    float acc = 0.f, cs = 0.f;
    #pragma unroll 8
    for (int r4 = 0; r4 < 128; r4 += 4) {
        float4 ev = *(const float4*)(eks + d * 132 + r4);
        float4 vv = *(const float4*)(vs  + e * 132 + r4);
        acc += ev.x * vv.x + ev.y * vv.y + ev.z * vv.z + ev.w * vv.w;
        cs  += ev.x + ev.y + ev.z + ev.w;
    }
    part[(size_t)bi * 256 + t] = acc;
    if (e == 0) pcs[(size_t)bi * 16 + d] = cs;
}

// ---------------------------------------------------------------- ctx reduce + fold wo -> mt frag (bf16)
__global__ __launch_bounds__(256) void build_mt_k(const float* __restrict__ part,
                                                  const float* __restrict__ pcs,
                                                  const float* __restrict__ wo,
                                                  short* __restrict__ mtfrag) {
    int b = blockIdx.x >> 3, nt = blockIdx.x & 7;
    int t = threadIdx.x;
    __shared__ float ctxL[2048];
    __shared__ float csL[128];
    __shared__ float woL[2048];
    #pragma unroll
    for (int i = 0; i < 8; i++) {
        int idx = i * 256 + t;
        int h = idx >> 8, rem = idx & 255;
        const float* pp = part + ((size_t)(b * 8 + h) * 32) * 256 + rem;
        float s = 0.f;
        #pragma unroll 8
        for (int c = 0; c < 32; c++) s += pp[(size_t)c * 256];
        ctxL[idx] = s;
    }
    if (t < 128) {
        int h = t >> 4, d = t & 15;
        const float* qq = pcs + ((size_t)(b * 8 + h) * 32) * 16 + d;
        float s = 0.f;
        #pragma unroll 8
        for (int c = 0; c < 32; c++) s += qq[(size_t)c * 16];
        csL[t] = s;
    }
    #pragma unroll
    for (int i = 0; i < 8; i++) {
        int idx = i * 256 + t;
        woL[idx] = wo[(size_t)(nt * 16) * DD + idx];
    }
    __syncthreads();
    int ks = (t >> 6) & 3, l = t & 63, r = l & 15, g = l >> 4;
    short8 o;
    #pragma unroll
    for (int i2 = 0; i2 < 8; i2++) {
        int k = 32 * ks + 8 * g + i2;
        float inv = 1.0f / csL[k];
        const float* wrow = woL + r * DD + (k >> 4) * 16;
        float s = 0.f;
        #pragma unroll
        for (int eo = 0; eo < 16; eo++) s += ctxL[k * 16 + eo] * wrow[eo];
        o[i2] = f2bf(s * inv);
    }
    ((short8*)(mtfrag + (size_t)b * 16384))[nt * 256 + t] = o;
}

// ---------------------------------------------------------------- S partials (x bf16, fx f32)
__global__ __launch_bounds__(256) void sbuild_p(const short* __restrict__ xf,
                                                const float* __restrict__ fx,
                                                float* __restrict__ part) {
    int b = blockIdx.x >> 6, chunk = blockIdx.x & 63;
    int t = threadIdx.x;
    __shared__ float xs[64 * 128], fs[64 * 128];
    const short* xb = xf + ((size_t)b * NN + chunk * 64) * DD;
    const float* fb = fx + ((size_t)b * NN + chunk * 64) * DD;
    float4* xs4 = (float4*)xs; float4* fs4 = (float4*)fs;
    const short8* xg = (const short8*)xb; const float4* fg = (const float4*)fb;
    #pragma unroll
    for (int i = 0; i < 4; i++) {
        int j = i * 256 + t;
        short8 s8 = xg[j];
        float4 a = {bf2f(s8[0]), bf2f(s8[1]), bf2f(s8[2]), bf2f(s8[3])};
        float4 c = {bf2f(s8[4]), bf2f(s8[5]), bf2f(s8[6]), bf2f(s8[7])};
        xs4[2 * j] = a; xs4[2 * j + 1] = c;
    }
    #pragma unroll
    for (int i = 0; i < 8; i++) {
        int j = i * 256 + t;
        fs4[j] = fg[j];
    }
    __syncthreads();
    int td = t >> 4, te = t & 15;
    float acc[8][8];
    #pragma unroll
    for (int a = 0; a < 8; a++)
        #pragma unroll
        for (int c = 0; c < 8; c++) acc[a][c] = 0.f;
    for (int r = 0; r < 64; r++) {
        float4 x0 = xs4[r * 32 + td * 2], x1 = xs4[r * 32 + td * 2 + 1];
        float4 f0 = fs4[r * 32 + te * 2], f1 = fs4[r * 32 + te * 2 + 1];
        float xv[8] = {x0.x, x0.y, x0.z, x0.w, x1.x, x1.y, x1.z, x1.w};
        float fv[8] = {f0.x, f0.y, f0.z, f0.w, f1.x, f1.y, f1.z, f1.w};
        #pragma unroll
        for (int a = 0; a < 8; a++)
            #pragma unroll
            for (int c = 0; c < 8; c++) acc[a][c] = fmaf(xv[a], fv[c], acc[a][c]);
    }
    float* pb = part + (size_t)blockIdx.x * 16384;
    int d0 = td * 8, e0 = te * 8;
    #pragma unroll
    for (int ei = 0; ei < 8; ei++) {
        float4 v0 = {acc[0][ei], acc[1][ei], acc[2][ei], acc[3][ei]};
        float4 v1 = {acc[4][ei], acc[5][ei], acc[6][ei], acc[7][ei]};
        float4* dst = (float4*)(pb + (size_t)(e0 + ei) * DD + d0);
        dst[0] = v0; dst[1] = v1;
    }
}

// ---------------------------------------------------------------- reduce S partials -> st frag (bf16)
__global__ __launch_bounds__(256) void sreduce(const float* __restrict__ part,
                                               short* __restrict__ stfrag) {
    int b = blockIdx.x >> 3;
    int j = (blockIdx.x & 7) * 256 + threadIdx.x;
    int nt = j >> 8, ks = (j >> 6) & 3, l = j & 63, r = l & 15, g = l >> 4;
    int c = nt * 16 + r, k0 = 32 * ks + 8 * g;
    const float* pb = part + (size_t)b * 64 * 16384 + (size_t)c * DD + k0;
    float s[8] = {0.f, 0.f, 0.f, 0.f, 0.f, 0.f, 0.f, 0.f};
    for (int ch = 0; ch < 64; ch++) {
        const float4* p4 = (const float4*)(pb + (size_t)ch * 16384);
        float4 u0 = p4[0], u1 = p4[1];
        s[0] += u0.x; s[1] += u0.y; s[2] += u0.z; s[3] += u0.w;
        s[4] += u1.x; s[5] += u1.y; s[6] += u1.z; s[7] += u1.w;
    }
    short8 o;
    #pragma unroll
    for (int i = 0; i < 8; i++) o[i] = f2bf(s[i]);
    ((short8*)(stfrag + (size_t)b * 16384))[j] = o;
}

// ---------------------------------------------------------------- launch
extern "C" void kernel_launch(void* const* d_in, const int* in_sizes, int n_in,
                              void* d_out, int out_size, void* d_ws, size_t ws_size,
                              hipStream_t stream) {
    const float* x    = (const float*)d_in[0];
    const float* fx   = (const float*)d_in[1];
    const float* ln1g = (const float*)d_in[2];
    const float* ln1b = (const float*)d_in[3];
    const float* wq   = (const float*)d_in[4];
    const float* wk   = (const float*)d_in[5];
    const float* wv   = (const float*)d_in[6];
    const float* wo   = (const float*)d_in[7];
    const float* bo   = (const float*)d_in[8];
    const float* ln2g = (const float*)d_in[9];
    const float* ln2b = (const float*)d_in[10];
    const float* w1   = (const float*)d_in[11];
    const float* b1   = (const float*)d_in[12];
    const float* w2   = (const float*)d_in[13];
    const float* b2   = (const float*)d_in[14];

    float* out = (float*)d_out;
    float* xfinal = out;
    float* fxout  = out + (size_t)MM * DD;

    float* ws = (float*)d_ws;
    float* xmid = ws;                             // 2,097,152 f32 (dead after K6; overlapped by partS)
    short* qb   = (short*)(ws + 2097152);         // bf16 (dead after K4; overlapped by partS)
    short* ekb  = (short*)(ws + 3145728);         // bf16 (dead after ctxp; overlapped by partS)
    short* vb   = (short*)(ws + 4194304);         // bf16 (dead after ctxp)
    short* yb   = (short*)(ws + 5242880);         // bf16
    short* h1b  = (short*)(ws + 6291456);         // bf16
    short* xbf  = (short*)(ws + 7340032);         // bf16, live till end
    float* tail = ws + 8388608;
    short* wfW  = (short*)tail;                   // 5*16384 shorts
    float* partC = tail + 40960;                  // 262144 f32
    float* pcs   = partC + 262144;                // 16384 f32
    short* mtf   = (short*)(pcs + 16384);         // 65536 shorts
    short* stf   = mtf + 65536;                   // 65536 shorts
    float* partS = ws;                            // 4,194,304 f32, overlaps xmid+qb+ekb (dead)

    wprep<<<40, 256, 0, stream>>>(wq, wk, wv, w1, w2, wfW);
    // fused LN1 + QKV + q-softmax + k-exp  (bf16 outputs)
    lnqkv<<<512, 256, 0, stream>>>(x, ln1g, ln1b, wfW, qb, ekb, vb);
    ctxp<<<1024, 256, 0, stream>>>(ekb, vb, partC, pcs);
    build_mt_k<<<32, 256, 0, stream>>>(partC, pcs, wo, mtf);
    // x_mid = q @ Mt + bo + x  (f32) ; y = LN2(x_mid) (bf16) — fused
    gemm_b<0, true, true, true, true, true, true><<<512, 256, 0, stream>>>(
        qb, mtf, bo, x, ln2g, ln2b, xmid, yb);
    // h1 = gelu(y @ w1 + b1) (bf16)
    gemm_b<1, true, false, false, false, true, false><<<512, 256, 0, stream>>>(
        yb, wfW + 3 * 16384, b1, nullptr, nullptr, nullptr, nullptr, h1b);
    // x_final = h1 @ w2 + b2 + x_mid -> output 0 (f32) + bf16 copy
    gemm_b<0, true, true, false, true, true, false><<<512, 256, 0, stream>>>(
        h1b, wfW + 4 * 16384, b2, xmid, nullptr, nullptr, xfinal, xbf);
    // quadratic update via S = x^T fx
    sbuild_p<<<256, 256, 0, stream>>>(xbf, fx, partS);
    sreduce<<<32, 256, 0, stream>>>(partS, stf);
    // fx_out = sigmoid(x @ S) -> output 1 (f32)
    gemm_b<2, false, false, true, true, false, false><<<512, 256, 0, stream>>>(
        xbf, stf, nullptr, nullptr, nullptr, nullptr, fxout, nullptr);
}

// Round 4
// 78.072 us; speedup vs baseline: 4.8395x; 1.4235x over previous
//
#include <hip/hip_runtime.h>
#include <math.h>

#define BB 4
#define NN 4096
#define DD 128
#define MM (BB*NN)   // 16384

typedef __attribute__((ext_vector_type(8))) short short8;
typedef __attribute__((ext_vector_type(4))) float f32x4;

__device__ inline short f2bf(float f) {
    unsigned u = __float_as_uint(f);
    u = (u + 0x7FFFu + ((u >> 16) & 1u)) >> 16;
    return (short)u;
}
__device__ inline float bf2f(short s) {
    return __uint_as_float(((unsigned)(unsigned short)s) << 16);
}
__device__ inline short8 pack_bf8(float4 a, float4 b) {
    short8 o;
    o[0] = f2bf(a.x); o[1] = f2bf(a.y); o[2] = f2bf(a.z); o[3] = f2bf(a.w);
    o[4] = f2bf(b.x); o[5] = f2bf(b.y); o[6] = f2bf(b.z); o[7] = f2bf(b.w);
    return o;
}
// swizzled LDS byte offset for a [32][128] bf16 tile (kills the 32-way
// stride-256B bank conflict on ds_read_b128; rows r and r+8 collide 2-way = free)
__device__ inline int swzoff(int row, int col) {
    return ((row * 128 + col) * 2) ^ ((row & 7) << 4);
}

// ---------------------------------------------------------------- weight preconvert to bf16 frag layout
// frag slot j = nt*256 + ks*64 + l ; elem i (0..7) = W[nt*16 + (l&15)][32*ks + 8*(l>>4) + i]
__global__ __launch_bounds__(256) void wprep(const float* __restrict__ w0, const float* __restrict__ w1,
                                             const float* __restrict__ w2, const float* __restrict__ w3,
                                             const float* __restrict__ w4, short* __restrict__ wf) {
    int m = blockIdx.x >> 3;
    int j = (blockIdx.x & 7) * 256 + threadIdx.x;
    const float* W = (m == 0) ? w0 : (m == 1) ? w1 : (m == 2) ? w2 : (m == 3) ? w3 : w4;
    int nt = j >> 8, ks = (j >> 6) & 3, l = j & 63, r = l & 15, g = l >> 4;
    const float* src = W + (size_t)(nt * 16 + r) * DD + 32 * ks + 8 * g;
    float4 a = *(const float4*)src;
    float4 b = *(const float4*)(src + 4);
    ((short8*)(wf + (size_t)m * 16384))[j] = pack_bf8(a, b);
}

// ---------------------------------------------------------------- fused LN1 + QKV (+q softmax, +k exp)
__global__ __launch_bounds__(256) void lnqkv(const float* __restrict__ x,
                                             const float* __restrict__ lng,
                                             const float* __restrict__ lnb,
                                             const short* __restrict__ wf,
                                             short* __restrict__ qb,
                                             short* __restrict__ ekb,
                                             short* __restrict__ vb) {
    int t = threadIdx.x;
    int block_row = blockIdx.x * 32;
    int w = t >> 6, l = t & 63, r = l & 15, g = l >> 4;
    int row0 = block_row + ((w >> 1) << 4);
    int nt0 = (w & 1) << 2;

    const float* ap = x + (size_t)(row0 + r) * DD + 8 * g;
    float4 av0[4], av1[4];
    #pragma unroll
    for (int ks = 0; ks < 4; ks++) {
        av0[ks] = *(const float4*)(ap + 32 * ks);
        av1[ks] = *(const float4*)(ap + 32 * ks + 4);
    }
    float s = 0.f, ss = 0.f;
    #pragma unroll
    for (int ks = 0; ks < 4; ks++) {
        float4 a = av0[ks], b = av1[ks];
        s  += a.x + a.y + a.z + a.w + b.x + b.y + b.z + b.w;
        ss += a.x*a.x + a.y*a.y + a.z*a.z + a.w*a.w + b.x*b.x + b.y*b.y + b.z*b.z + b.w*b.w;
    }
    s  += __shfl_xor(s, 16);  s  += __shfl_xor(s, 32);
    ss += __shfl_xor(ss, 16); ss += __shfl_xor(ss, 32);
    float mu = s * (1.0f / DD);
    float var = ss * (1.0f / DD) - mu * mu;
    float rs = rsqrtf(var + 1e-6f);

    short8 af[4];
    #pragma unroll
    for (int ks = 0; ks < 4; ks++) {
        float4 g0 = *(const float4*)(lng + 32 * ks + 8 * g);
        float4 g1 = *(const float4*)(lng + 32 * ks + 8 * g + 4);
        float4 b0 = *(const float4*)(lnb + 32 * ks + 8 * g);
        float4 b1 = *(const float4*)(lnb + 32 * ks + 8 * g + 4);
        float4 n0, n1;
        n0.x = (av0[ks].x - mu) * rs * g0.x + b0.x;
        n0.y = (av0[ks].y - mu) * rs * g0.y + b0.y;
        n0.z = (av0[ks].z - mu) * rs * g0.z + b0.z;
        n0.w = (av0[ks].w - mu) * rs * g0.w + b0.w;
        n1.x = (av1[ks].x - mu) * rs * g1.x + b1.x;
        n1.y = (av1[ks].y - mu) * rs * g1.y + b1.y;
        n1.z = (av1[ks].z - mu) * rs * g1.z + b1.z;
        n1.w = (av1[ks].w - mu) * rs * g1.w + b1.w;
        af[ks] = pack_bf8(n0, n1);
    }

    f32x4 acc[3][4];
    #pragma unroll
    for (int m = 0; m < 3; m++)
        #pragma unroll
        for (int n = 0; n < 4; n++) acc[m][n] = (f32x4){0.f, 0.f, 0.f, 0.f};
    const short8* wp8 = (const short8*)wf;
    #pragma unroll
    for (int ks = 0; ks < 4; ks++)
        #pragma unroll
        for (int m = 0; m < 3; m++)
            #pragma unroll
            for (int n = 0; n < 4; n++)
                acc[m][n] = __builtin_amdgcn_mfma_f32_16x16x32_bf16(
                    af[ks], wp8[(size_t)m * 2048 + ((nt0 + n) * 4 + ks) * 64 + l], acc[m][n], 0, 0, 0);

    #pragma unroll
    for (int n = 0; n < 4; n++) {
        int col = (nt0 + n) * 16 + r;
        #pragma unroll
        for (int j = 0; j < 4; j++) {
            size_t row = (size_t)(row0 + 4 * g + j);
            float e = __expf(acc[0][n][j]);
            float sm = e;
            sm += __shfl_xor(sm, 1); sm += __shfl_xor(sm, 2);
            sm += __shfl_xor(sm, 4); sm += __shfl_xor(sm, 8);
            qb[row * DD + col]  = f2bf(e / sm);
            ekb[row * DD + col] = f2bf(__expf(acc[1][n][j]));
            vb[row * DD + col]  = f2bf(acc[2][n][j]);
        }
    }
}

// ---------------------------------------------------------------- fused mid-section:
// xmid = q@Mt + bo + x (regs) ; y = LN2(xmid) ; h1 = gelu(y@w1+b1) ; xf = h1@w2 + b2 + xmid
__global__ __launch_bounds__(256) void fused_mid(const short* __restrict__ qb,
                                                 const short* __restrict__ mtf,
                                                 const float* __restrict__ bo,
                                                 const float* __restrict__ x,
                                                 const float* __restrict__ ln2g,
                                                 const float* __restrict__ ln2b,
                                                 const short* __restrict__ w1f,
                                                 const float* __restrict__ b1,
                                                 const short* __restrict__ w2f,
                                                 const float* __restrict__ b2,
                                                 float* __restrict__ xfinal,
                                                 short* __restrict__ xbf) {
    __shared__ __align__(16) char ex[32 * 128 * 2];   // 8 KB swizzled exchange tile
    __shared__ float redS[4][16], redSS[4][16];
    int t = threadIdx.x;
    int block_row = blockIdx.x * 32;
    int w = t >> 6, l = t & 63, r = l & 15, g = l >> 4;
    int rh = w >> 1, nt0 = (w & 1) << 2;
    int row0 = block_row + rh * 16;

    // ---- GEMM1: q @ Mt (per-batch Mt)
    const short8* ap = (const short8*)(qb + (size_t)(row0 + r) * DD + 8 * g);
    short8 af[4];
    #pragma unroll
    for (int ks = 0; ks < 4; ks++) af[ks] = ap[ks * 4];
    const short8* mp = (const short8*)(mtf + (size_t)(block_row >> 12) * 16384);
    f32x4 acc[4];
    #pragma unroll
    for (int n = 0; n < 4; n++) acc[n] = (f32x4){0.f, 0.f, 0.f, 0.f};
    #pragma unroll
    for (int ks = 0; ks < 4; ks++)
        #pragma unroll
        for (int n = 0; n < 4; n++)
            acc[n] = __builtin_amdgcn_mfma_f32_16x16x32_bf16(
                af[ks], mp[((nt0 + n) * 4 + ks) * 64 + l], acc[n], 0, 0, 0);

    float vv[4][4];   // xmid, stays in registers
    #pragma unroll
    for (int n = 0; n < 4; n++) {
        int col = (nt0 + n) * 16 + r;
        float bv = bo[col];
        #pragma unroll
        for (int j = 0; j < 4; j++)
            vv[n][j] = acc[n][j] + bv + x[(size_t)(row0 + 4 * g + j) * DD + col];
    }

    // ---- LN2 (cross-lane over r, cross-wave over the two col-half waves)
    #pragma unroll
    for (int j = 0; j < 4; j++) {
        float s  = vv[0][j] + vv[1][j] + vv[2][j] + vv[3][j];
        float s2 = vv[0][j]*vv[0][j] + vv[1][j]*vv[1][j] + vv[2][j]*vv[2][j] + vv[3][j]*vv[3][j];
        s  += __shfl_xor(s, 1);  s  += __shfl_xor(s, 2);  s  += __shfl_xor(s, 4);  s  += __shfl_xor(s, 8);
        s2 += __shfl_xor(s2, 1); s2 += __shfl_xor(s2, 2); s2 += __shfl_xor(s2, 4); s2 += __shfl_xor(s2, 8);
        if (r == 0) { redS[w][4 * g + j] = s; redSS[w][4 * g + j] = s2; }
    }
    __syncthreads();
    int base = w & 2;
    // ---- y = LN(xmid), store to swizzled LDS
    #pragma unroll
    for (int j = 0; j < 4; j++) {
        int rr = 4 * g + j;
        float S  = redS[base][rr]  + redS[base + 1][rr];
        float SS = redSS[base][rr] + redSS[base + 1][rr];
        float mu = S * (1.0f / DD);
        float var = SS * (1.0f / DD) - mu * mu;
        float rs = rsqrtf(var + 1e-6f);
        int rowL = rh * 16 + rr;
        #pragma unroll
        for (int n = 0; n < 4; n++) {
            int col = (nt0 + n) * 16 + r;
            float y = (vv[n][j] - mu) * rs * ln2g[col] + ln2b[col];
            *(short*)(ex + swzoff(rowL, col)) = f2bf(y);
        }
    }
    __syncthreads();
    // ---- re-fragment y
    int rrow = rh * 16 + r;
    short8 yf[4];
    #pragma unroll
    for (int ks = 0; ks < 4; ks++)
        yf[ks] = *(const short8*)(ex + swzoff(rrow, 32 * ks + 8 * g));
    __syncthreads();   // all reads done before h1 overwrites
    // ---- GEMM2: y @ w1, gelu
    const short8* w1p = (const short8*)w1f;
    f32x4 acc2[4];
    #pragma unroll
    for (int n = 0; n < 4; n++) acc2[n] = (f32x4){0.f, 0.f, 0.f, 0.f};
    #pragma unroll
    for (int ks = 0; ks < 4; ks++)
        #pragma unroll
        for (int n = 0; n < 4; n++)
            acc2[n] = __builtin_amdgcn_mfma_f32_16x16x32_bf16(
                yf[ks], w1p[((nt0 + n) * 4 + ks) * 64 + l], acc2[n], 0, 0, 0);
    #pragma unroll
    for (int n = 0; n < 4; n++) {
        int col = (nt0 + n) * 16 + r;
        float bv = b1[col];
        #pragma unroll
        for (int j = 0; j < 4; j++) {
            float v = acc2[n][j] + bv;
            v = 0.5f * v * (1.0f + erff(v * 0.70710678118654752f));
            *(short*)(ex + swzoff(rh * 16 + 4 * g + j, col)) = f2bf(v);
        }
    }
    __syncthreads();
    // ---- re-fragment h1
    short8 hf[4];
    #pragma unroll
    for (int ks = 0; ks < 4; ks++)
        hf[ks] = *(const short8*)(ex + swzoff(rrow, 32 * ks + 8 * g));
    // ---- GEMM3: h1 @ w2 + b2 + xmid
    const short8* w2p = (const short8*)w2f;
    f32x4 acc3[4];
    #pragma unroll
    for (int n = 0; n < 4; n++) acc3[n] = (f32x4){0.f, 0.f, 0.f, 0.f};
    #pragma unroll
    for (int ks = 0; ks < 4; ks++)
        #pragma unroll
        for (int n = 0; n < 4; n++)
            acc3[n] = __builtin_amdgcn_mfma_f32_16x16x32_bf16(
                hf[ks], w2p[((nt0 + n) * 4 + ks) * 64 + l], acc3[n], 0, 0, 0);
    #pragma unroll
    for (int n = 0; n < 4; n++) {
        int col = (nt0 + n) * 16 + r;
        float bv = b2[col];
        #pragma unroll
        for (int j = 0; j < 4; j++) {
            float v = acc3[n][j] + bv + vv[n][j];
            size_t row = (size_t)(row0 + 4 * g + j);
            xfinal[row * DD + col] = v;
            xbf[row * DD + col] = f2bf(v);
        }
    }
}

// ---------------------------------------------------------------- ctx partials per (b,h,512-row chunk)
__global__ __launch_bounds__(256) void ctxp(const short* __restrict__ ek, const short* __restrict__ v,
                                            float* __restrict__ part, float* __restrict__ pcs) {
    int bi = blockIdx.x;                 // ((b*8+h)*8) + chunk
    int chunk = bi & 7, bh = bi >> 3, h = bh & 7, b = bh >> 3;
    int t = threadIdx.x;
    __shared__ float eks[16 * 132], vs[16 * 132];
    const short* eb = ek + (size_t)b * NN * DD + h * 16;
    const short* vb = v  + (size_t)b * NN * DD + h * 16;
    int d = t >> 4, e = t & 15;
    float acc = 0.f, cs = 0.f;
    for (int sc = 0; sc < 4; sc++) {
        int nb = chunk * 512 + sc * 128;
        __syncthreads();
        {
            int row = t >> 1, half = t & 1;
            short8 es = *(const short8*)(eb + (size_t)(nb + row) * DD + half * 8);
            short8 vsv = *(const short8*)(vb + (size_t)(nb + row) * DD + half * 8);
            #pragma unroll
            for (int i = 0; i < 8; i++) {
                int c = half * 8 + i;
                eks[c * 132 + row] = bf2f(es[i]);
                vs [c * 132 + row] = bf2f(vsv[i]);
            }
        }
        __syncthreads();
        #pragma unroll 8
        for (int r4 = 0; r4 < 128; r4 += 4) {
            float4 ev = *(const float4*)(eks + d * 132 + r4);
            float4 vv = *(const float4*)(vs  + e * 132 + r4);
            acc += ev.x * vv.x + ev.y * vv.y + ev.z * vv.z + ev.w * vv.w;
            cs  += ev.x + ev.y + ev.z + ev.w;
        }
    }
    part[(size_t)bi * 256 + t] = acc;
    if (e == 0) pcs[(size_t)bi * 16 + d] = cs;
}

// ---------------------------------------------------------------- ctx reduce + fold wo -> mt frag (bf16)
__global__ __launch_bounds__(256) void build_mt_k(const float* __restrict__ part,
                                                  const float* __restrict__ pcs,
                                                  const float* __restrict__ wo,
                                                  short* __restrict__ mtfrag) {
    int b = blockIdx.x >> 3, nt = blockIdx.x & 7;
    int t = threadIdx.x;
    __shared__ float ctxL[2048];
    __shared__ float csL[128];
    __shared__ float woL[2048];
    #pragma unroll
    for (int i = 0; i < 8; i++) {
        int idx = i * 256 + t;
        int h = idx >> 8, rem = idx & 255;
        const float* pp = part + ((size_t)(b * 8 + h) * 8) * 256 + rem;
        float s = 0.f;
        #pragma unroll
        for (int c = 0; c < 8; c++) s += pp[(size_t)c * 256];
        ctxL[idx] = s;
    }
    if (t < 128) {
        int h = t >> 4, d = t & 15;
        const float* qq = pcs + ((size_t)(b * 8 + h) * 8) * 16 + d;
        float s = 0.f;
        #pragma unroll
        for (int c = 0; c < 8; c++) s += qq[(size_t)c * 16];
        csL[t] = s;
    }
    #pragma unroll
    for (int i = 0; i < 8; i++) {
        int idx = i * 256 + t;
        woL[idx] = wo[(size_t)(nt * 16) * DD + idx];
    }
    __syncthreads();
    int ks = (t >> 6) & 3, l = t & 63, r = l & 15, g = l >> 4;
    short8 o;
    #pragma unroll
    for (int i2 = 0; i2 < 8; i2++) {
        int k = 32 * ks + 8 * g + i2;
        float inv = 1.0f / csL[k];
        const float* wrow = woL + r * DD + (k >> 4) * 16;
        float s = 0.f;
        #pragma unroll
        for (int eo = 0; eo < 16; eo++) s += ctxL[k * 16 + eo] * wrow[eo];
        o[i2] = f2bf(s * inv);
    }
    ((short8*)(mtfrag + (size_t)b * 16384))[nt * 256 + t] = o;
}

// ---------------------------------------------------------------- S partials (x bf16, fx f32) -> bf16
__global__ __launch_bounds__(256) void sbuild_p(const short* __restrict__ xf,
                                                const float* __restrict__ fx,
                                                short* __restrict__ part) {
    int b = blockIdx.x >> 6, chunk = blockIdx.x & 63;
    int t = threadIdx.x;
    __shared__ float xs[64 * 128], fs[64 * 128];
    const short* xb = xf + ((size_t)b * NN + chunk * 64) * DD;
    const float* fb = fx + ((size_t)b * NN + chunk * 64) * DD;
    float4* xs4 = (float4*)xs; float4* fs4 = (float4*)fs;
    const short8* xg = (const short8*)xb; const float4* fg = (const float4*)fb;
    #pragma unroll
    for (int i = 0; i < 4; i++) {
        int j = i * 256 + t;
        short8 s8 = xg[j];
        float4 a = {bf2f(s8[0]), bf2f(s8[1]), bf2f(s8[2]), bf2f(s8[3])};
        float4 c = {bf2f(s8[4]), bf2f(s8[5]), bf2f(s8[6]), bf2f(s8[7])};
        xs4[2 * j] = a; xs4[2 * j + 1] = c;
    }
    #pragma unroll
    for (int i = 0; i < 8; i++) {
        int j = i * 256 + t;
        fs4[j] = fg[j];
    }
    __syncthreads();
    int td = t >> 4, te = t & 15;
    float acc[8][8];
    #pragma unroll
    for (int a = 0; a < 8; a++)
        #pragma unroll
        for (int c = 0; c < 8; c++) acc[a][c] = 0.f;
    for (int r = 0; r < 64; r++) {
        float4 x0 = xs4[r * 32 + td * 2], x1 = xs4[r * 32 + td * 2 + 1];
        float4 f0 = fs4[r * 32 + te * 2], f1 = fs4[r * 32 + te * 2 + 1];
        float xv[8] = {x0.x, x0.y, x0.z, x0.w, x1.x, x1.y, x1.z, x1.w};
        float fv[8] = {f0.x, f0.y, f0.z, f0.w, f1.x, f1.y, f1.z, f1.w};
        #pragma unroll
        for (int a = 0; a < 8; a++)
            #pragma unroll
            for (int c = 0; c < 8; c++) acc[a][c] = fmaf(xv[a], fv[c], acc[a][c]);
    }
    short* pb = part + (size_t)blockIdx.x * 16384;
    int d0 = td * 8, e0 = te * 8;
    #pragma unroll
    for (int ei = 0; ei < 8; ei++) {
        short8 o;
        #pragma unroll
        for (int i = 0; i < 8; i++) o[i] = f2bf(acc[i][ei]);
        *(short8*)(pb + (size_t)(e0 + ei) * DD + d0) = o;
    }
}

// ---------------------------------------------------------------- reduce S partials -> st frag (bf16)
__global__ __launch_bounds__(256) void sreduce(const short* __restrict__ part,
                                               short* __restrict__ stfrag) {
    int b = blockIdx.x >> 3;
    int j = (blockIdx.x & 7) * 256 + threadIdx.x;
    int nt = j >> 8, ks = (j >> 6) & 3, l = j & 63, r = l & 15, g = l >> 4;
    int c = nt * 16 + r, k0 = 32 * ks + 8 * g;
    const short* pb = part + (size_t)b * 64 * 16384 + (size_t)c * DD + k0;
    float s[8] = {0.f, 0.f, 0.f, 0.f, 0.f, 0.f, 0.f, 0.f};
    for (int ch = 0; ch < 64; ch++) {
        short8 u = *(const short8*)(pb + (size_t)ch * 16384);
        #pragma unroll
        for (int i = 0; i < 8; i++) s[i] += bf2f(u[i]);
    }
    short8 o;
    #pragma unroll
    for (int i = 0; i < 8; i++) o[i] = f2bf(s[i]);
    ((short8*)(stfrag + (size_t)b * 16384))[j] = o;
}

// ---------------------------------------------------------------- final sigmoid GEMM (per-batch S)
__global__ __launch_bounds__(256) void gemm_sig(const short* __restrict__ A,
                                                const short* __restrict__ wfrag,
                                                float* __restrict__ Cf) {
    int t = threadIdx.x;
    int block_row = blockIdx.x * 32;
    int w = t >> 6, l = t & 63, r = l & 15, g = l >> 4;
    int row0 = block_row + ((w >> 1) << 4);
    int nt0 = (w & 1) << 2;
    const short8* ap = (const short8*)(A + (size_t)(row0 + r) * DD + 8 * g);
    short8 af[4];
    #pragma unroll
    for (int ks = 0; ks < 4; ks++) af[ks] = ap[ks * 4];
    const short8* wp8 = (const short8*)(wfrag + (size_t)(block_row >> 12) * 16384);
    f32x4 acc[4];
    #pragma unroll
    for (int n = 0; n < 4; n++) acc[n] = (f32x4){0.f, 0.f, 0.f, 0.f};
    #pragma unroll
    for (int ks = 0; ks < 4; ks++)
        #pragma unroll
        for (int n = 0; n < 4; n++)
            acc[n] = __builtin_amdgcn_mfma_f32_16x16x32_bf16(
                af[ks], wp8[((nt0 + n) * 4 + ks) * 64 + l], acc[n], 0, 0, 0);
    #pragma unroll
    for (int n = 0; n < 4; n++) {
        int col = (nt0 + n) * 16 + r;
        #pragma unroll
        for (int j = 0; j < 4; j++) {
            float v = 1.0f / (1.0f + __expf(-acc[n][j]));
            Cf[(size_t)(row0 + 4 * g + j) * DD + col] = v;
        }
    }
}

// ---------------------------------------------------------------- launch
extern "C" void kernel_launch(void* const* d_in, const int* in_sizes, int n_in,
                              void* d_out, int out_size, void* d_ws, size_t ws_size,
                              hipStream_t stream) {
    const float* x    = (const float*)d_in[0];
    const float* fx   = (const float*)d_in[1];
    const float* ln1g = (const float*)d_in[2];
    const float* ln1b = (const float*)d_in[3];
    const float* wq   = (const float*)d_in[4];
    const float* wk   = (const float*)d_in[5];
    const float* wv   = (const float*)d_in[6];
    const float* wo   = (const float*)d_in[7];
    const float* bo   = (const float*)d_in[8];
    const float* ln2g = (const float*)d_in[9];
    const float* ln2b = (const float*)d_in[10];
    const float* w1   = (const float*)d_in[11];
    const float* b1   = (const float*)d_in[12];
    const float* w2   = (const float*)d_in[13];
    const float* b2   = (const float*)d_in[14];

    float* out = (float*)d_out;
    float* xfinal = out;
    float* fxout  = out + (size_t)MM * DD;

    float* ws = (float*)d_ws;
    short* qb   = (short*)ws;                      // 2M shorts
    short* ekb  = (short*)(ws + 1048576);
    short* vb   = (short*)(ws + 2097152);
    short* xbf  = (short*)(ws + 3145728);
    short* partSb = (short*)(ws + 4194304);        // 4M shorts (4b*64ch*16384)
    float* tail = ws + 6291456;
    short* wfW  = (short*)tail;                    // 5*16384 shorts
    float* partC = tail + 40960;                   // 256 blocks * 256 f32
    float* pcs   = partC + 65536;                  // 256*16 f32
    short* mtf   = (short*)(pcs + 4096);           // 4*16384 shorts
    short* stf   = mtf + 65536;                    // 4*16384 shorts

    wprep<<<40, 256, 0, stream>>>(wq, wk, wv, w1, w2, wfW);
    lnqkv<<<512, 256, 0, stream>>>(x, ln1g, ln1b, wfW, qb, ekb, vb);
    ctxp<<<256, 256, 0, stream>>>(ekb, vb, partC, pcs);
    build_mt_k<<<32, 256, 0, stream>>>(partC, pcs, wo, mtf);
    fused_mid<<<512, 256, 0, stream>>>(qb, mtf, bo, x, ln2g, ln2b,
                                       wfW + 3 * 16384, b1, wfW + 4 * 16384, b2,
                                       xfinal, xbf);
    sbuild_p<<<256, 256, 0, stream>>>(xbf, fx, partSb);
    sreduce<<<32, 256, 0, stream>>>(partSb, stf);
    gemm_sig<<<512, 256, 0, stream>>>(xbf, stf, fxout);
}